// Round 6
// baseline (580.557 us; speedup 1.0000x reference)
//
#include <hip/hip_runtime.h>

#define N_   16384
#define D_   256
#define E_   262144
#define ET_  278528   // E_ + N_ (self loops)
#define DI_  512
#define CH_  512      // scan chunks
#define CL_  32       // chunk length (CH_*CL_ == N_)

typedef __attribute__((ext_vector_type(8))) short short8;
typedef __attribute__((ext_vector_type(4))) float f32x4;

static __device__ __forceinline__ float wave_sum(float v){
#pragma unroll
  for (int m = 1; m < 64; m <<= 1) v += __shfl_xor(v, m);
  return v;
}
static __device__ __forceinline__ float wave_max(float v){
#pragma unroll
  for (int m = 1; m < 64; m <<= 1) v = fmaxf(v, __shfl_xor(v, m));
  return v;
}
static __device__ __forceinline__ float silu_f(float x){ return x / (1.f + __expf(-x)); }
static __device__ __forceinline__ unsigned short f2b(float f){   // fp32 -> bf16 RNE
  unsigned u = __float_as_uint(f);
  return (unsigned short)((u + 0x7fffu + ((u >> 16) & 1u)) >> 16);
}

// ---------------------------------------------------------------- diagnostic marker (fires only if ws too small)
__global__ __launch_bounds__(256) void marker_kernel(float* __restrict__ out){
  out[threadIdx.x] = 1e9f;
}

// ---------------------------------------------------------------- permute x (3,N,256) -> xcat (N,768)
__global__ __launch_bounds__(256) void permute_kernel(const float* __restrict__ x, float* __restrict__ xcat){
  int idx = blockIdx.x * 256 + threadIdx.x;      // over 3*16384*64 float4
  if (idx >= 3 * N_ * 64) return;
  int d4  = idx & 63;
  int n   = (idx >> 6) & (N_ - 1);
  int hop = idx >> 20;
  float4 v = ((const float4*)x)[((size_t)hop << 20) + ((size_t)n << 6) + d4];
  ((float4*)xcat)[(size_t)n * 192 + hop * 64 + d4] = v;
}

// ---------------------------------------------------------------- weight transpose+convert: W[K x N] fp32 -> BT[Npad x K] bf16
__global__ __launch_bounds__(256) void wconv_kernel(const float* __restrict__ W, int K, int N,
                                                    unsigned short* __restrict__ BT){
  __shared__ float t[32][33];
  const int k0 = blockIdx.x * 32, n0 = blockIdx.y * 32;
  const int tr = threadIdx.x & 31, tc = threadIdx.x >> 5;
#pragma unroll
  for (int r = tc; r < 32; r += 8) {
    int k = k0 + r, n = n0 + tr;
    t[r][tr] = (k < K && n < N) ? W[(size_t)k * N + n] : 0.f;
  }
  __syncthreads();
#pragma unroll
  for (int r = tc; r < 32; r += 8) {
    int n = n0 + r, k = k0 + tr;
    BT[(size_t)n * K + k] = f2b(t[tr][r]);
  }
}

// ---------------------------------------------------------------- bf16 MFMA GEMM
// C[row_map[m], c_off+n] = A(M x K fp32) @ BT^T (BT is [Npad x K] bf16) + bias
// tile 128x64, 4 waves (2x2), per-wave 64x32 = 4x2 frags of 16x16, BK=32.
#define ALD 40   // LDS row stride in bf16 elems (80B): 16B aligned, <=2-way bank conflict
__global__ __launch_bounds__(256) void mgemm_kernel(
    const float* __restrict__ A, int lda,
    const unsigned short* __restrict__ BT, int ldbt, int N,
    float* __restrict__ C, int ldc, int c_off,
    const float* __restrict__ bias, const int* __restrict__ row_map, int K)
{
  __shared__ __align__(16) unsigned short Al[128 * ALD];
  __shared__ __align__(16) unsigned short Bl[64 * ALD];
  const int tid = threadIdx.x;
  const int lane = tid & 63;
  const int wid = tid >> 6;
  const int wr = wid >> 1;           // wave row half (64 rows)
  const int wc = wid & 1;            // wave col half (32 cols)
  const int m0 = blockIdx.x * 128;
  const int n0 = blockIdx.y * 64;
  const int fr = lane & 15, fq = lane >> 4;
  f32x4 acc[4][2] = {};
  for (int k0 = 0; k0 < K; k0 += 32) {
    // stage A: 128x32 fp32 -> bf16 (4 float4 per thread)
#pragma unroll
    for (int i = 0; i < 4; ++i) {
      int f = tid + i * 256;                 // 0..1023
      int r = f >> 3, kq = (f & 7) << 2;
      float4 v = *(const float4*)&A[(size_t)(m0 + r) * lda + k0 + kq];
      unsigned long long pk = (unsigned long long)f2b(v.x)
                            | ((unsigned long long)f2b(v.y) << 16)
                            | ((unsigned long long)f2b(v.z) << 32)
                            | ((unsigned long long)f2b(v.w) << 48);
      *(unsigned long long*)&Al[r * ALD + kq] = pk;
    }
    // stage BT: 64 cols x 32 k bf16 (16B per thread)
    {
      int c = tid >> 2, kq = (tid & 3) << 3;
      short8 v = *(const short8*)&BT[(size_t)(n0 + c) * ldbt + k0 + kq];
      *(short8*)&Bl[c * ALD + kq] = v;
    }
    __syncthreads();
    short8 af[4], bf[2];
#pragma unroll
    for (int m = 0; m < 4; ++m) af[m] = *(const short8*)&Al[(wr * 64 + m * 16 + fr) * ALD + fq * 8];
#pragma unroll
    for (int n = 0; n < 2; ++n) bf[n] = *(const short8*)&Bl[(wc * 32 + n * 16 + fr) * ALD + fq * 8];
#pragma unroll
    for (int n = 0; n < 2; ++n)
#pragma unroll
      for (int m = 0; m < 4; ++m)
        acc[m][n] = __builtin_amdgcn_mfma_f32_16x16x32_bf16(af[m], bf[n], acc[m][n], 0, 0, 0);
    __syncthreads();
  }
  // epilogue: C col=lane&15, row=(lane>>4)*4+j  [m89-verified]
#pragma unroll
  for (int m = 0; m < 4; ++m)
#pragma unroll
    for (int n = 0; n < 2; ++n) {
      int col = n0 + wc * 32 + n * 16 + fr;
      if (col >= N) continue;
      float bv = bias ? bias[col] : 0.f;
#pragma unroll
      for (int j = 0; j < 4; ++j) {
        int row = m0 + wr * 64 + m * 16 + fq * 4 + j;
        int orow = row_map ? row_map[row] : row;
        C[(size_t)orow * ldc + c_off + col] = acc[m][n][j] + bv;
      }
    }
}

// ---------------------------------------------------------------- rowwise LN(256) + silu, in place
__global__ __launch_bounds__(256) void ln_silu_kernel(float* __restrict__ x, const float* __restrict__ g, const float* __restrict__ b){
  __shared__ float red[4];
  const int row = blockIdx.x; const int t = threadIdx.x;
  float v = x[(size_t)row * 256 + t];
  float sv = wave_sum(v);
  if ((t & 63) == 0) red[t >> 6] = sv;
  __syncthreads();
  float mean = (red[0] + red[1] + red[2] + red[3]) * (1.f / 256.f);
  __syncthreads();
  float dv = v - mean;
  float sq = wave_sum(dv * dv);
  if ((t & 63) == 0) red[t >> 6] = sq;
  __syncthreads();
  float var = (red[0] + red[1] + red[2] + red[3]) * (1.f / 256.f);
  float o = dv * rsqrtf(var + 1e-5f) * g[t] + b[t];
  x[(size_t)row * 256 + t] = silu_f(o);
}

// ---------------------------------------------------------------- per-node attention logits
__global__ __launch_bounds__(256) void att_scores_kernel(const float* __restrict__ h, const float* __restrict__ asr,
                                                         const float* __restrict__ adt, float* __restrict__ as_, float* __restrict__ ad_){
  int wid = threadIdx.x >> 6, lane = threadIdx.x & 63;
  int n = blockIdx.x * 4 + wid;
  float s1 = 0.f, s2 = 0.f;
  for (int f = lane; f < 256; f += 64) {
    float hv = h[(size_t)n * 256 + f];
    s1 = fmaf(hv, asr[f], s1); s2 = fmaf(hv, adt[f], s2);
  }
  s1 = wave_sum(s1); s2 = wave_sum(s2);
  if (lane == 0) { as_[n] = s1; ad_[n] = s2; }
}

// ---------------------------------------------------------------- CSR build
__global__ __launch_bounds__(256) void count_kernel(const int* __restrict__ ei, int* __restrict__ cnt_in, int* __restrict__ deg_out){
  int i = blockIdx.x * 256 + threadIdx.x;
  if (i >= ET_) return;
  int dst = (i < E_) ? ei[E_ + i] : (i - E_);
  atomicAdd(&cnt_in[dst], 1);
  if (i < E_) atomicAdd(&deg_out[ei[i]], 1);
}

__global__ __launch_bounds__(1024) void scan_offsets_kernel(const int* __restrict__ cnt, int* __restrict__ off, int* __restrict__ cursor){
  __shared__ int part[1024];
  int t = threadIdx.x;
  int base = t * 16;
  int local[16]; int s = 0;
#pragma unroll
  for (int i = 0; i < 16; ++i) { local[i] = s; s += cnt[base + i]; }
  part[t] = s; __syncthreads();
  for (int d = 1; d < 1024; d <<= 1) {
    int val = part[t];
    int add = (t >= d) ? part[t - d] : 0;
    __syncthreads();
    part[t] = val + add;
    __syncthreads();
  }
  int prev = (t > 0) ? part[t - 1] : 0;
#pragma unroll
  for (int i = 0; i < 16; ++i) { int o = prev + local[i]; off[base + i] = o; cursor[base + i] = o; }
  if (t == 1023) off[N_] = part[1023];
}

__global__ __launch_bounds__(256) void scatter_kernel(const int* __restrict__ ei, int* __restrict__ cursor, int* __restrict__ csr){
  int i = blockIdx.x * 256 + threadIdx.x;
  if (i >= ET_) return;
  int dst = (i < E_) ? ei[E_ + i] : (i - E_);
  int pos = atomicAdd(&cursor[dst], 1);
  csr[pos] = i;
}

// ---------------------------------------------------------------- GAT softmax + aggregate (gather, no float atomics). writes cat[:, :256]
__global__ __launch_bounds__(256) void gat_agg_kernel(const int* __restrict__ ei, const int* __restrict__ off, const int* __restrict__ csr,
                                                      const float* __restrict__ as_, const float* __restrict__ ad_,
                                                      const float* __restrict__ h, const float* __restrict__ gat_b, float* __restrict__ cat){
  const int dst = blockIdx.x;
  const int t = threadIdx.x;
  const int o0 = off[dst];
  int deg = off[dst + 1] - o0;
  if (deg > 1024) deg = 1024;   // cannot occur (mean deg ~17); guards LDS
  __shared__ int   ssrc[1024];
  __shared__ float se[1024];
  __shared__ float red[4];
  const float adv = ad_[dst];
  float m = -1e30f;
  for (int j = t; j < deg; j += 256) {
    int eid = csr[o0 + j];
    int src = (eid < E_) ? ei[eid] : (eid - E_);
    float e = as_[src] + adv;
    e = (e >= 0.f) ? e : 0.2f * e;
    ssrc[j] = src; se[j] = e;
    m = fmaxf(m, e);
  }
  m = wave_max(m);
  if ((t & 63) == 0) red[t >> 6] = m;
  __syncthreads();
  m = fmaxf(fmaxf(red[0], red[1]), fmaxf(red[2], red[3]));
  __syncthreads();
  float dsum = 0.f;
  for (int j = t; j < deg; j += 256) { float x = __expf(se[j] - m); se[j] = x; dsum += x; }
  dsum = wave_sum(dsum);
  if ((t & 63) == 0) red[t >> 6] = dsum;
  __syncthreads();
  float inv = 1.f / (red[0] + red[1] + red[2] + red[3]);
  float acc = gat_b[t];
  for (int j = 0; j < deg; ++j) acc = fmaf(se[j] * inv, h[(size_t)ssrc[j] * 256 + t], acc);
  cat[(size_t)dst * 512 + t] = acc;
}

// ---------------------------------------------------------------- sort key: (enc32(deg + noise*0.1) << 32) | idx
// __fmul_rn/__fadd_rn: forbid FMA contraction so rounding bit-matches the
// reference's separate mul-then-add (near-tie keys decide the mamba ordering).
__global__ __launch_bounds__(256) void key_kernel(const int* __restrict__ degO, const float* __restrict__ noise, unsigned long long* __restrict__ keys){
  int n = blockIdx.x * 256 + threadIdx.x;
  if (n >= N_) return;
  float k = __fadd_rn((float)degO[n], __fmul_rn(noise[n], 0.1f));
  unsigned u = __float_as_uint(k);
  u = (u & 0x80000000u) ? ~u : (u | 0x80000000u);
  keys[n] = ((unsigned long long)u << 32) | (unsigned)n;
}

// ---------------------------------------------------------------- O(N^2) rank sort, j-split for occupancy:
// block (bx,by): for 256 i's of bx, count keys < key_i within segment by (512 keys)
__global__ __launch_bounds__(256) void rank_part_kernel(const unsigned long long* __restrict__ keys, int* __restrict__ rank){
  __shared__ unsigned long long tile[512];
  const int i = blockIdx.x * 256 + threadIdx.x;
  const unsigned long long ki = keys[i];
  const int base = blockIdx.y * 512;
  for (int j = threadIdx.x; j < 512; j += 256) tile[j] = keys[base + j];
  __syncthreads();
  int r = 0;
#pragma unroll 16
  for (int j = 0; j < 512; ++j) r += (tile[j] < ki);
  atomicAdd(&rank[i], r);
}
__global__ __launch_bounds__(256) void rank_scatter_kernel(const int* __restrict__ rank, int* __restrict__ sidx){
  int i = blockIdx.x * 256 + threadIdx.x;
  sidx[rank[i]] = i;
}

// ---------------------------------------------------------------- u0 = xf[sidx]
__global__ __launch_bounds__(64) void gather_kernel(const float* __restrict__ xf, const int* __restrict__ sidx, float* __restrict__ u0){
  int i = blockIdx.x, t = threadIdx.x;
  ((float4*)u0)[(size_t)i * 64 + t] = ((const float4*)xf)[(size_t)sidx[i] * 64 + t];
}

// ---------------------------------------------------------------- causal depthwise conv (k=4) + silu; in = xz[:, :512] (stride 1024)
__global__ __launch_bounds__(256) void conv_silu_kernel(const float* __restrict__ xz, const float* __restrict__ cw, float* __restrict__ xm){
  int idx = blockIdx.x * 256 + threadIdx.x;
  if (idx >= N_ * DI_) return;
  int n = idx >> 9, c = idx & 511;
  float acc = 0.f;
#pragma unroll
  for (int k = 0; k < 4; ++k) {
    int nn = n - 3 + k;
    if (nn >= 0) acc = fmaf(xz[(size_t)nn * 1024 + c], cw[c * 4 + k], acc);
  }
  xm[idx] = silu_f(acc);
}

// ================================================================ chunk-parallel selective scan, thread-per-channel
// recurrence h[s] = exp(Ac[s]*dt)*h[s] + dt*B[s]; y[n,d] = sum_s h[s]*B[n,s].
// thread = channel d: h[16]+Ac[16] in registers, B/x0 via LDS broadcast.
// layout b_final/init: [c][s][d] (d fastest => coalesced)
__global__ __launch_bounds__(256) void scan_p1_kernel(const float* __restrict__ xdbl,
    const float* __restrict__ dt_w, const float* __restrict__ dt_b, const float* __restrict__ A_log,
    float* __restrict__ a_sum, float* __restrict__ b_final)
{
  const int d = blockIdx.x * 256 + threadIdx.x;
  const int c = blockIdx.y;
  float Ac[16];
#pragma unroll
  for (int s = 0; s < 16; ++s) Ac[s] = -__expf(A_log[d * 16 + s]);
  const float dwv = dt_w[d], dbv = dt_b[d];
  __shared__ float sx[CL_];
  __shared__ float sB[CL_][16];
  for (int idx = threadIdx.x; idx < CL_ * 17; idx += 256) {   // contiguous 544-float slab
    float v = xdbl[(size_t)c * (CL_ * 17) + idx];
    int row = idx / 17, col = idx - row * 17;
    if (col == 0) sx[row] = v; else sB[row][col - 1] = v;
  }
  __syncthreads();
  float h[16] = {};
  float dts = 0.f;
  for (int i = 0; i < CL_; ++i) {
    float v = fmaf(sx[i], dwv, dbv);
    float dtv = fmaxf(v, 0.f) + log1pf(__expf(-fabsf(v)));   // softplus
    dts += dtv;
#pragma unroll
    for (int s = 0; s < 16; ++s)
      h[s] = fmaf(__expf(Ac[s] * dtv), h[s], dtv * sB[i][s]);
  }
  a_sum[c * 512 + d] = dts;
#pragma unroll
  for (int s = 0; s < 16; ++s) b_final[((size_t)c * 16 + s) * 512 + d] = h[s];
}

__global__ __launch_bounds__(256) void scan_mid_kernel(const float* __restrict__ a_sum,
    const float* __restrict__ b_final, const float* __restrict__ A_log, float* __restrict__ init)
{
  const int t = blockIdx.x * 256 + threadIdx.x;   // 8192 threads = (s,d)
  const int s = t >> 9, d = t & 511;
  const float Ac = -__expf(A_log[d * 16 + s]);
  float h = 0.f;
  float an = a_sum[d];
  float bn = b_final[(size_t)s * 512 + d];
  for (int c = 0; c < CH_; ++c) {
    float a = an, b = bn;
    if (c + 1 < CH_) {                 // prefetch next chunk's operator
      an = a_sum[(c + 1) * 512 + d];
      bn = b_final[((size_t)(c + 1) * 16 + s) * 512 + d];
    }
    init[((size_t)c * 16 + s) * 512 + d] = h;
    h = fmaf(__expf(Ac * a), h, b);
  }
}

// p3 fuses ymod: writes final y = (scan_y + xm*D) * silu(z) into xz[:, :512]
__global__ __launch_bounds__(256) void scan_p3_kernel(const float* __restrict__ xdbl,
    const float* __restrict__ dt_w, const float* __restrict__ dt_b, const float* __restrict__ A_log,
    const float* __restrict__ init, const float* __restrict__ xm, const float* __restrict__ Dp,
    float* __restrict__ xz)
{
  const int d = blockIdx.x * 256 + threadIdx.x;
  const int c = blockIdx.y;
  float Ac[16];
#pragma unroll
  for (int s = 0; s < 16; ++s) Ac[s] = -__expf(A_log[d * 16 + s]);
  const float dwv = dt_w[d], dbv = dt_b[d], dpv = Dp[d];
  __shared__ float sx[CL_];
  __shared__ float sB[CL_][16];
  for (int idx = threadIdx.x; idx < CL_ * 17; idx += 256) {
    float v = xdbl[(size_t)c * (CL_ * 17) + idx];
    int row = idx / 17, col = idx - row * 17;
    if (col == 0) sx[row] = v; else sB[row][col - 1] = v;
  }
  __syncthreads();
  float h[16];
#pragma unroll
  for (int s = 0; s < 16; ++s) h[s] = init[((size_t)c * 16 + s) * 512 + d];
  for (int i = 0; i < CL_; ++i) {
    const int n = c * CL_ + i;
    float v = fmaf(sx[i], dwv, dbv);
    float dtv = fmaxf(v, 0.f) + log1pf(__expf(-fabsf(v)));
    float y = 0.f;
#pragma unroll
    for (int s = 0; s < 16; ++s) {
      float Bv = sB[i][s];
      h[s] = fmaf(__expf(Ac[s] * dtv), h[s], dtv * Bv);
      y = fmaf(h[s], Bv, y);
    }
    float yv = fmaf(xm[(size_t)n * 512 + d], dpv, y);
    float z = xz[(size_t)n * 1024 + 512 + d];
    xz[(size_t)n * 1024 + d] = yv * silu_f(z);
  }
}

// ================================================================ host
extern "C" void kernel_launch(void* const* d_in, const int* in_sizes, int n_in,
                              void* d_out, int out_size, void* d_ws, size_t ws_size,
                              hipStream_t stream)
{
  (void)in_sizes; (void)n_in; (void)out_size;
  const float* x         = (const float*)d_in[0];
  const int*   ei        = (const int*)d_in[1];
  const float* pnoise    = (const float*)d_in[2];
  const float* hop_w     = (const float*)d_in[3];
  const float* hop_b     = (const float*)d_in[4];
  const float* hop_ln_g  = (const float*)d_in[5];
  const float* hop_ln_b  = (const float*)d_in[6];
  const float* gat_w     = (const float*)d_in[7];
  const float* att_src   = (const float*)d_in[8];
  const float* att_dst   = (const float*)d_in[9];
  const float* gat_b     = (const float*)d_in[10];
  const float* in_proj_w = (const float*)d_in[11];
  const float* conv_w    = (const float*)d_in[12];
  const float* x_proj_w  = (const float*)d_in[13];
  const float* dt_w      = (const float*)d_in[14];
  const float* dt_b      = (const float*)d_in[15];
  const float* A_log     = (const float*)d_in[16];
  const float* D_param   = (const float*)d_in[17];
  const float* out_w     = (const float*)d_in[18];
  const float* out_b     = (const float*)d_in[19];
  const float* mlp_w1    = (const float*)d_in[20];
  const float* mlp_b1    = (const float*)d_in[21];
  const float* mlp_ln_g  = (const float*)d_in[22];
  const float* mlp_ln_b  = (const float*)d_in[23];
  const float* mlp_w2    = (const float*)d_in[24];
  const float* mlp_b2    = (const float*)d_in[25];
  float* out = (float*)d_out;

  char* w = (char*)d_ws;
  auto alloc = [&](size_t bytes) -> void* {
    void* p = (void*)w; w += (bytes + 255) & ~(size_t)255; return p;
  };
  float* xz   = (float*)alloc((size_t)N_ * 1024 * 4);  // 64 MiB
  float* xf   = (float*)alloc((size_t)N_ * 256 * 4);   // 16 MiB
  float* h    = (float*)alloc((size_t)N_ * 256 * 4);   // 16 MiB
  float* xm   = (float*)alloc((size_t)N_ * 512 * 4);   // 32 MiB
  float* cat  = (float*)alloc((size_t)N_ * 512 * 4);   // 32 MiB
  float* xdbl = (float*)alloc((size_t)N_ * 17 * 4);
  float* as_  = (float*)alloc((size_t)N_ * 4);
  float* ad_  = (float*)alloc((size_t)N_ * 4);
  int* cnt    = (int*)alloc((size_t)N_ * 4);    // cnt, degO, rank contiguous for one memset
  int* degO   = (int*)alloc((size_t)N_ * 4);
  int* rank   = (int*)alloc((size_t)N_ * 4);
  int* cursor = (int*)alloc((size_t)N_ * 4);
  int* off    = (int*)alloc((size_t)(N_ + 1) * 4);
  int* sidx   = (int*)alloc((size_t)N_ * 4);
  int* csr    = (int*)alloc((size_t)ET_ * 4);
  unsigned long long* keys = (unsigned long long*)alloc((size_t)N_ * 8);
  // bf16 transposed weight panels [Npad x K]
  unsigned short* bt_hop = (unsigned short*)alloc((size_t)256 * 768 * 2);
  unsigned short* bt_gat = (unsigned short*)alloc((size_t)256 * 256 * 2);
  unsigned short* bt_inp = (unsigned short*)alloc((size_t)1024 * 256 * 2);
  unsigned short* bt_xp  = (unsigned short*)alloc((size_t)64 * 512 * 2);
  unsigned short* bt_out = (unsigned short*)alloc((size_t)256 * 512 * 2);
  unsigned short* bt_m1  = (unsigned short*)alloc((size_t)256 * 512 * 2);
  unsigned short* bt_m2  = (unsigned short*)alloc((size_t)256 * 256 * 2);
  float* u0      = h;        // alias (h dead after gat_agg)
  float* mlp1    = xf;       // alias (xf dead after gather; mlp1 written step 15)
  float* b_final = h;        // alias (16 MiB: CH_*16*512*4; h dead after in_proj gemm)
  float* init    = xf;       // alias (16 MiB; xf dead after gather, reborn as mlp1 later)
  float* a_sum   = (float*)csr;   // alias (1 MiB; csr dead after gat_agg)
  size_t needed = (size_t)(w - (char*)d_ws);
  if (needed > ws_size) {                    // diagnostic: absmax ~1e9 => ws too small
    marker_kernel<<<1, 256, 0, stream>>>(out);
    return;
  }

  hipMemsetAsync(cnt, 0, 3 * (size_t)N_ * 4, stream);   // cnt + degO + rank

  // 0. weight panels (bf16, transposed)
  wconv_kernel<<<dim3(24, 8),  256, 0, stream>>>(hop_w,     768, 256,  bt_hop);
  wconv_kernel<<<dim3(8, 8),   256, 0, stream>>>(gat_w,     256, 256,  bt_gat);
  wconv_kernel<<<dim3(8, 32),  256, 0, stream>>>(in_proj_w, 256, 1024, bt_inp);
  wconv_kernel<<<dim3(16, 2),  256, 0, stream>>>(x_proj_w,  512, 17,   bt_xp);
  wconv_kernel<<<dim3(16, 8),  256, 0, stream>>>(out_w,     512, 256,  bt_out);
  wconv_kernel<<<dim3(16, 8),  256, 0, stream>>>(mlp_w1,    512, 256,  bt_m1);
  wconv_kernel<<<dim3(8, 8),   256, 0, stream>>>(mlp_w2,    256, 256,  bt_m2);

  // 1. xcat = permute(x)
  permute_kernel<<<(3 * N_ * 64) / 256, 256, 0, stream>>>(x, xz);
  // 2. xf = silu(LN(xcat @ hop_w + hop_b))
  mgemm_kernel<<<dim3(128, 4), 256, 0, stream>>>(xz, 768, bt_hop, 768, 256, xf, 256, 0, hop_b, nullptr, 768);
  ln_silu_kernel<<<N_, 256, 0, stream>>>(xf, hop_ln_g, hop_ln_b);
  // 3. h = xf @ gat_w
  mgemm_kernel<<<dim3(128, 4), 256, 0, stream>>>(xf, 256, bt_gat, 256, 256, h, 256, 0, nullptr, nullptr, 256);
  // 4. attention logits per node
  att_scores_kernel<<<N_ / 4, 256, 0, stream>>>(h, att_src, att_dst, as_, ad_);
  // 5. CSR by dst (incl self loops) + out-degree
  count_kernel<<<(ET_ + 255) / 256, 256, 0, stream>>>(ei, cnt, degO);
  scan_offsets_kernel<<<1, 1024, 0, stream>>>(cnt, off, cursor);
  scatter_kernel<<<(ET_ + 255) / 256, 256, 0, stream>>>(ei, cursor, csr);
  // 6. GAT softmax+aggregate -> cat[:, :256]
  gat_agg_kernel<<<N_, 256, 0, stream>>>(ei, off, csr, as_, ad_, h, gat_b, cat);
  // 7. stable argsort(deg + noise*0.1): rank reduction split over 32 j-segments
  key_kernel<<<N_ / 256, 256, 0, stream>>>(degO, pnoise, keys);
  rank_part_kernel<<<dim3(N_ / 256, 32), 256, 0, stream>>>(keys, rank);
  rank_scatter_kernel<<<N_ / 256, 256, 0, stream>>>(rank, sidx);
  // 8. u0 = xf[sidx]; xz = u0 @ in_proj_w   (overwrites xcat)
  gather_kernel<<<N_, 64, 0, stream>>>(xf, sidx, u0);
  mgemm_kernel<<<dim3(128, 16), 256, 0, stream>>>(u0, 256, bt_inp, 256, 1024, xz, 1024, 0, nullptr, nullptr, 256);
  // 9. depthwise causal conv + silu -> xm
  conv_silu_kernel<<<(N_ * DI_) / 256, 256, 0, stream>>>(xz, conv_w, xm);
  // 10. x_dbl = xm @ x_proj_w (N=17)
  mgemm_kernel<<<dim3(128, 1), 256, 0, stream>>>(xm, 512, bt_xp, 512, 17, xdbl, 17, 0, nullptr, nullptr, 512);
  // 11+12+13. chunk-parallel selective scan (dt + ymod fused) -> xz[:, :512]
  scan_p1_kernel<<<dim3(2, CH_), 256, 0, stream>>>(xdbl, dt_w, dt_b, A_log, a_sum, b_final);
  scan_mid_kernel<<<32, 256, 0, stream>>>(a_sum, b_final, A_log, init);
  scan_p3_kernel<<<dim3(2, CH_), 256, 0, stream>>>(xdbl, dt_w, dt_b, A_log, init, xm, D_param, xz);
  // 14. x_mamba = y @ out_w + out_b, scattered (un-permuted) into cat[:, 256:]
  mgemm_kernel<<<dim3(128, 4), 256, 0, stream>>>(xz, 1024, bt_out, 512, 256, cat, 512, 256, out_b, sidx, 512);
  // 15. MLP
  mgemm_kernel<<<dim3(128, 4), 256, 0, stream>>>(cat, 512, bt_m1, 512, 256, mlp1, 256, 0, mlp_b1, nullptr, 512);
  ln_silu_kernel<<<N_, 256, 0, stream>>>(mlp1, mlp_ln_g, mlp_ln_b);
  mgemm_kernel<<<dim3(128, 4), 256, 0, stream>>>(mlp1, 256, bt_m2, 256, 256, out, 256, 0, mlp_b2, nullptr, 256);
}

// Round 7
// 513.046 us; speedup vs baseline: 1.1316x; 1.1316x over previous
//
#include <hip/hip_runtime.h>

#define N_   16384
#define D_   256
#define E_   262144
#define ET_  278528   // E_ + N_ (self loops)
#define DI_  512
#define CH_  512      // scan chunks
#define CL_  32       // chunk length (CH_*CL_ == N_)
#define GS_  16       // chunk-operator group size
#define NG_  32       // number of groups (CH_/GS_)

typedef __attribute__((ext_vector_type(8))) short short8;
typedef __attribute__((ext_vector_type(4))) float f32x4;

static __device__ __forceinline__ float wave_sum(float v){
#pragma unroll
  for (int m = 1; m < 64; m <<= 1) v += __shfl_xor(v, m);
  return v;
}
static __device__ __forceinline__ float wave_max(float v){
#pragma unroll
  for (int m = 1; m < 64; m <<= 1) v = fmaxf(v, __shfl_xor(v, m));
  return v;
}
static __device__ __forceinline__ float silu_f(float x){ return x / (1.f + __expf(-x)); }
static __device__ __forceinline__ unsigned short f2b(float f){   // fp32 -> bf16 RNE
  unsigned u = __float_as_uint(f);
  return (unsigned short)((u + 0x7fffu + ((u >> 16) & 1u)) >> 16);
}

// ---------------------------------------------------------------- diagnostic marker (fires only if ws too small)
__global__ __launch_bounds__(256) void marker_kernel(float* __restrict__ out){
  out[threadIdx.x] = 1e9f;
}

// ---------------------------------------------------------------- permute x (3,N,256) -> xcat (N,768)
__global__ __launch_bounds__(256) void permute_kernel(const float* __restrict__ x, float* __restrict__ xcat){
  int idx = blockIdx.x * 256 + threadIdx.x;      // over 3*16384*64 float4
  if (idx >= 3 * N_ * 64) return;
  int d4  = idx & 63;
  int n   = (idx >> 6) & (N_ - 1);
  int hop = idx >> 20;
  float4 v = ((const float4*)x)[((size_t)hop << 20) + ((size_t)n << 6) + d4];
  ((float4*)xcat)[(size_t)n * 192 + hop * 64 + d4] = v;
}

// ---------------------------------------------------------------- weight transpose+convert: W[K x N] fp32 -> BT[Npad x K] bf16
__global__ __launch_bounds__(256) void wconv_kernel(const float* __restrict__ W, int K, int N,
                                                    unsigned short* __restrict__ BT){
  __shared__ float t[32][33];
  const int k0 = blockIdx.x * 32, n0 = blockIdx.y * 32;
  const int tr = threadIdx.x & 31, tc = threadIdx.x >> 5;
#pragma unroll
  for (int r = tc; r < 32; r += 8) {
    int k = k0 + r, n = n0 + tr;
    t[r][tr] = (k < K && n < N) ? W[(size_t)k * N + n] : 0.f;
  }
  __syncthreads();
#pragma unroll
  for (int r = tc; r < 32; r += 8) {
    int n = n0 + r, k = k0 + tr;
    BT[(size_t)n * K + k] = f2b(t[tr][r]);
  }
}

// ---------------------------------------------------------------- bf16 MFMA GEMM
// C[row_map[m], c_off+n] = A(M x K fp32) @ BT^T (BT is [Npad x K] bf16) + bias
// tile 128x64, 4 waves (2x2), per-wave 64x32 = 4x2 frags of 16x16, BK=32.
#define ALD 40   // LDS row stride in bf16 elems (80B): 16B aligned, <=2-way bank conflict
__global__ __launch_bounds__(256) void mgemm_kernel(
    const float* __restrict__ A, int lda,
    const unsigned short* __restrict__ BT, int ldbt, int N,
    float* __restrict__ C, int ldc, int c_off,
    const float* __restrict__ bias, const int* __restrict__ row_map, int K)
{
  __shared__ __align__(16) unsigned short Al[128 * ALD];
  __shared__ __align__(16) unsigned short Bl[64 * ALD];
  const int tid = threadIdx.x;
  const int lane = tid & 63;
  const int wid = tid >> 6;
  const int wr = wid >> 1;           // wave row half (64 rows)
  const int wc = wid & 1;            // wave col half (32 cols)
  const int m0 = blockIdx.x * 128;
  const int n0 = blockIdx.y * 64;
  const int fr = lane & 15, fq = lane >> 4;
  f32x4 acc[4][2] = {};
  for (int k0 = 0; k0 < K; k0 += 32) {
    // stage A: 128x32 fp32 -> bf16 (4 float4 per thread)
#pragma unroll
    for (int i = 0; i < 4; ++i) {
      int f = tid + i * 256;                 // 0..1023
      int r = f >> 3, kq = (f & 7) << 2;
      float4 v = *(const float4*)&A[(size_t)(m0 + r) * lda + k0 + kq];
      unsigned long long pk = (unsigned long long)f2b(v.x)
                            | ((unsigned long long)f2b(v.y) << 16)
                            | ((unsigned long long)f2b(v.z) << 32)
                            | ((unsigned long long)f2b(v.w) << 48);
      *(unsigned long long*)&Al[r * ALD + kq] = pk;
    }
    // stage BT: 64 cols x 32 k bf16 (16B per thread)
    {
      int c = tid >> 2, kq = (tid & 3) << 3;
      short8 v = *(const short8*)&BT[(size_t)(n0 + c) * ldbt + k0 + kq];
      *(short8*)&Bl[c * ALD + kq] = v;
    }
    __syncthreads();
    short8 af[4], bf[2];
#pragma unroll
    for (int m = 0; m < 4; ++m) af[m] = *(const short8*)&Al[(wr * 64 + m * 16 + fr) * ALD + fq * 8];
#pragma unroll
    for (int n = 0; n < 2; ++n) bf[n] = *(const short8*)&Bl[(wc * 32 + n * 16 + fr) * ALD + fq * 8];
#pragma unroll
    for (int n = 0; n < 2; ++n)
#pragma unroll
      for (int m = 0; m < 4; ++m)
        acc[m][n] = __builtin_amdgcn_mfma_f32_16x16x32_bf16(af[m], bf[n], acc[m][n], 0, 0, 0);
    __syncthreads();
  }
  // epilogue: C col=lane&15, row=(lane>>4)*4+j  [m89-verified]
#pragma unroll
  for (int m = 0; m < 4; ++m)
#pragma unroll
    for (int n = 0; n < 2; ++n) {
      int col = n0 + wc * 32 + n * 16 + fr;
      if (col >= N) continue;
      float bv = bias ? bias[col] : 0.f;
#pragma unroll
      for (int j = 0; j < 4; ++j) {
        int row = m0 + wr * 64 + m * 16 + fq * 4 + j;
        int orow = row_map ? row_map[row] : row;
        C[(size_t)orow * ldc + c_off + col] = acc[m][n][j] + bv;
      }
    }
}

// ---------------------------------------------------------------- rowwise LN(256) + silu, in place
__global__ __launch_bounds__(256) void ln_silu_kernel(float* __restrict__ x, const float* __restrict__ g, const float* __restrict__ b){
  __shared__ float red[4];
  const int row = blockIdx.x; const int t = threadIdx.x;
  float v = x[(size_t)row * 256 + t];
  float sv = wave_sum(v);
  if ((t & 63) == 0) red[t >> 6] = sv;
  __syncthreads();
  float mean = (red[0] + red[1] + red[2] + red[3]) * (1.f / 256.f);
  __syncthreads();
  float dv = v - mean;
  float sq = wave_sum(dv * dv);
  if ((t & 63) == 0) red[t >> 6] = sq;
  __syncthreads();
  float var = (red[0] + red[1] + red[2] + red[3]) * (1.f / 256.f);
  float o = dv * rsqrtf(var + 1e-5f) * g[t] + b[t];
  x[(size_t)row * 256 + t] = silu_f(o);
}

// ---------------------------------------------------------------- per-node attention logits
__global__ __launch_bounds__(256) void att_scores_kernel(const float* __restrict__ h, const float* __restrict__ asr,
                                                         const float* __restrict__ adt, float* __restrict__ as_, float* __restrict__ ad_){
  int wid = threadIdx.x >> 6, lane = threadIdx.x & 63;
  int n = blockIdx.x * 4 + wid;
  float s1 = 0.f, s2 = 0.f;
  for (int f = lane; f < 256; f += 64) {
    float hv = h[(size_t)n * 256 + f];
    s1 = fmaf(hv, asr[f], s1); s2 = fmaf(hv, adt[f], s2);
  }
  s1 = wave_sum(s1); s2 = wave_sum(s2);
  if (lane == 0) { as_[n] = s1; ad_[n] = s2; }
}

// ---------------------------------------------------------------- CSR build
__global__ __launch_bounds__(256) void count_kernel(const int* __restrict__ ei, int* __restrict__ cnt_in, int* __restrict__ deg_out){
  int i = blockIdx.x * 256 + threadIdx.x;
  if (i >= ET_) return;
  int dst = (i < E_) ? ei[E_ + i] : (i - E_);
  atomicAdd(&cnt_in[dst], 1);
  if (i < E_) atomicAdd(&deg_out[ei[i]], 1);
}

__global__ __launch_bounds__(1024) void scan_offsets_kernel(const int* __restrict__ cnt, int* __restrict__ off, int* __restrict__ cursor){
  __shared__ int part[1024];
  int t = threadIdx.x;
  int base = t * 16;
  int local[16]; int s = 0;
#pragma unroll
  for (int i = 0; i < 16; ++i) { local[i] = s; s += cnt[base + i]; }
  part[t] = s; __syncthreads();
  for (int d = 1; d < 1024; d <<= 1) {
    int val = part[t];
    int add = (t >= d) ? part[t - d] : 0;
    __syncthreads();
    part[t] = val + add;
    __syncthreads();
  }
  int prev = (t > 0) ? part[t - 1] : 0;
#pragma unroll
  for (int i = 0; i < 16; ++i) { int o = prev + local[i]; off[base + i] = o; cursor[base + i] = o; }
  if (t == 1023) off[N_] = part[1023];
}

__global__ __launch_bounds__(256) void scatter_kernel(const int* __restrict__ ei, int* __restrict__ cursor, int* __restrict__ csr){
  int i = blockIdx.x * 256 + threadIdx.x;
  if (i >= ET_) return;
  int dst = (i < E_) ? ei[E_ + i] : (i - E_);
  int pos = atomicAdd(&cursor[dst], 1);
  csr[pos] = i;
}

// ---------------------------------------------------------------- GAT softmax + aggregate (gather, no float atomics). writes cat[:, :256]
__global__ __launch_bounds__(256) void gat_agg_kernel(const int* __restrict__ ei, const int* __restrict__ off, const int* __restrict__ csr,
                                                      const float* __restrict__ as_, const float* __restrict__ ad_,
                                                      const float* __restrict__ h, const float* __restrict__ gat_b, float* __restrict__ cat){
  const int dst = blockIdx.x;
  const int t = threadIdx.x;
  const int o0 = off[dst];
  int deg = off[dst + 1] - o0;
  if (deg > 1024) deg = 1024;   // cannot occur (mean deg ~17); guards LDS
  __shared__ int   ssrc[1024];
  __shared__ float se[1024];
  __shared__ float red[4];
  const float adv = ad_[dst];
  float m = -1e30f;
  for (int j = t; j < deg; j += 256) {
    int eid = csr[o0 + j];
    int src = (eid < E_) ? ei[eid] : (eid - E_);
    float e = as_[src] + adv;
    e = (e >= 0.f) ? e : 0.2f * e;
    ssrc[j] = src; se[j] = e;
    m = fmaxf(m, e);
  }
  m = wave_max(m);
  if ((t & 63) == 0) red[t >> 6] = m;
  __syncthreads();
  m = fmaxf(fmaxf(red[0], red[1]), fmaxf(red[2], red[3]));
  __syncthreads();
  float dsum = 0.f;
  for (int j = t; j < deg; j += 256) { float x = __expf(se[j] - m); se[j] = x; dsum += x; }
  dsum = wave_sum(dsum);
  if ((t & 63) == 0) red[t >> 6] = dsum;
  __syncthreads();
  float inv = 1.f / (red[0] + red[1] + red[2] + red[3]);
  float acc = gat_b[t];
  for (int j = 0; j < deg; ++j) acc = fmaf(se[j] * inv, h[(size_t)ssrc[j] * 256 + t], acc);
  cat[(size_t)dst * 512 + t] = acc;
}

// ---------------------------------------------------------------- sort key: (enc32(deg + noise*0.1) << 32) | idx
__global__ __launch_bounds__(256) void key_kernel(const int* __restrict__ degO, const float* __restrict__ noise, unsigned long long* __restrict__ keys){
  int n = blockIdx.x * 256 + threadIdx.x;
  if (n >= N_) return;
  float k = __fadd_rn((float)degO[n], __fmul_rn(noise[n], 0.1f));
  unsigned u = __float_as_uint(k);
  u = (u & 0x80000000u) ? ~u : (u | 0x80000000u);
  keys[n] = ((unsigned long long)u << 32) | (unsigned)n;
}

// ---------------------------------------------------------------- O(N^2) rank sort, j-split for occupancy
__global__ __launch_bounds__(256) void rank_part_kernel(const unsigned long long* __restrict__ keys, int* __restrict__ rank){
  __shared__ unsigned long long tile[512];
  const int i = blockIdx.x * 256 + threadIdx.x;
  const unsigned long long ki = keys[i];
  const int base = blockIdx.y * 512;
  for (int j = threadIdx.x; j < 512; j += 256) tile[j] = keys[base + j];
  __syncthreads();
  int r = 0;
#pragma unroll 16
  for (int j = 0; j < 512; ++j) r += (tile[j] < ki);
  atomicAdd(&rank[i], r);
}
__global__ __launch_bounds__(256) void rank_scatter_kernel(const int* __restrict__ rank, int* __restrict__ sidx){
  int i = blockIdx.x * 256 + threadIdx.x;
  sidx[rank[i]] = i;
}

// ---------------------------------------------------------------- u0 = xf[sidx]
__global__ __launch_bounds__(64) void gather_kernel(const float* __restrict__ xf, const int* __restrict__ sidx, float* __restrict__ u0){
  int i = blockIdx.x, t = threadIdx.x;
  ((float4*)u0)[(size_t)i * 64 + t] = ((const float4*)xf)[(size_t)sidx[i] * 64 + t];
}

// ---------------------------------------------------------------- causal depthwise conv (k=4) + silu; in = xz[:, :512] (stride 1024)
__global__ __launch_bounds__(256) void conv_silu_kernel(const float* __restrict__ xz, const float* __restrict__ cw, float* __restrict__ xm){
  int idx = blockIdx.x * 256 + threadIdx.x;
  if (idx >= N_ * DI_) return;
  int n = idx >> 9, c = idx & 511;
  float acc = 0.f;
#pragma unroll
  for (int k = 0; k < 4; ++k) {
    int nn = n - 3 + k;
    if (nn >= 0) acc = fmaf(xz[(size_t)nn * 1024 + c], cw[c * 4 + k], acc);
  }
  xm[idx] = silu_f(acc);
}

// ================================================================ chunk-parallel selective scan, thread-per-channel
// h[s] = exp(Ac[s]*dt)*h[s] + dt*B[s]; y[n,d] = sum_s h[s]*B[n,s].
// layouts: b_final/init [c][s][d]; group ops ga[g][d], gb[g][s][d]; d fastest.
__global__ __launch_bounds__(256) void scan_p1_kernel(const float* __restrict__ xdbl,
    const float* __restrict__ dt_w, const float* __restrict__ dt_b, const float* __restrict__ A_log,
    float* __restrict__ a_sum, float* __restrict__ b_final)
{
  const int d = blockIdx.x * 256 + threadIdx.x;
  const int c = blockIdx.y;
  float Ac[16];
#pragma unroll
  for (int s = 0; s < 16; ++s) Ac[s] = -__expf(A_log[d * 16 + s]);
  const float dwv = dt_w[d], dbv = dt_b[d];
  __shared__ float sx[CL_];
  __shared__ float sB[CL_][16];
  for (int idx = threadIdx.x; idx < CL_ * 17; idx += 256) {   // contiguous 544-float slab
    float v = xdbl[(size_t)c * (CL_ * 17) + idx];
    int row = idx / 17, col = idx - row * 17;
    if (col == 0) sx[row] = v; else sB[row][col - 1] = v;
  }
  __syncthreads();
  float h[16] = {};
  float dts = 0.f;
  for (int i = 0; i < CL_; ++i) {
    float v = fmaf(sx[i], dwv, dbv);
    float dtv = fmaxf(v, 0.f) + log1pf(__expf(-fabsf(v)));   // softplus
    dts += dtv;
#pragma unroll
    for (int s = 0; s < 16; ++s)
      h[s] = fmaf(__expf(Ac[s] * dtv), h[s], dtv * sB[i][s]);
  }
  a_sum[c * 512 + d] = dts;
#pragma unroll
  for (int s = 0; s < 16; ++s) b_final[((size_t)c * 16 + s) * 512 + d] = h[s];
}

// mid level 1: compose GS_ chunk ops per group -> (ga, gb)
__global__ __launch_bounds__(256) void scan_mid1_kernel(const float* __restrict__ a_sum,
    const float* __restrict__ b_final, const float* __restrict__ A_log,
    float* __restrict__ ga, float* __restrict__ gb)
{
  const int tid = blockIdx.x * 256 + threadIdx.x;   // NG_*16*512
  const int d = tid & 511;
  const int s = (tid >> 9) & 15;
  const int g = tid >> 13;
  const float Ac = -__expf(A_log[d * 16 + s]);
  const int c0 = g * GS_;
  float ag = 0.f, Bg = 0.f;
  float an = a_sum[c0 * 512 + d];
  float bn = b_final[((size_t)c0 * 16 + s) * 512 + d];
#pragma unroll
  for (int k = 0; k < GS_; ++k) {
    float a = an, b = bn;
    if (k + 1 < GS_) {
      an = a_sum[(c0 + k + 1) * 512 + d];
      bn = b_final[((size_t)(c0 + k + 1) * 16 + s) * 512 + d];
    }
    Bg = fmaf(__expf(Ac * a), Bg, b);
    ag += a;
  }
  gb[((size_t)g * 16 + s) * 512 + d] = Bg;
  if (s == 0) ga[g * 512 + d] = ag;
}

// mid level 2: scan NG_ group ops fully in registers (static unroll)
__global__ __launch_bounds__(256) void scan_mid2_kernel(const float* __restrict__ ga,
    const float* __restrict__ gb, const float* __restrict__ A_log, float* __restrict__ ginit)
{
  const int tid = blockIdx.x * 256 + threadIdx.x;   // 8192 = (s,d)
  const int d = tid & 511;
  const int s = tid >> 9;
  const float Ac = -__expf(A_log[d * 16 + s]);
  float gar[NG_], gbr[NG_];
#pragma unroll
  for (int g = 0; g < NG_; ++g) {
    gar[g] = ga[g * 512 + d];
    gbr[g] = gb[((size_t)g * 16 + s) * 512 + d];
  }
  float h = 0.f;
#pragma unroll
  for (int g = 0; g < NG_; ++g) {
    ginit[((size_t)g * 16 + s) * 512 + d] = h;
    h = fmaf(__expf(Ac * gar[g]), h, gbr[g]);
  }
}

// mid level 3: expand group-entry states to per-chunk init
__global__ __launch_bounds__(256) void scan_mid3_kernel(const float* __restrict__ a_sum,
    const float* __restrict__ b_final, const float* __restrict__ A_log,
    const float* __restrict__ ginit, float* __restrict__ init)
{
  const int tid = blockIdx.x * 256 + threadIdx.x;
  const int d = tid & 511;
  const int s = (tid >> 9) & 15;
  const int g = tid >> 13;
  const float Ac = -__expf(A_log[d * 16 + s]);
  const int c0 = g * GS_;
  float h = ginit[((size_t)g * 16 + s) * 512 + d];
  float an = a_sum[c0 * 512 + d];
  float bn = b_final[((size_t)c0 * 16 + s) * 512 + d];
#pragma unroll
  for (int k = 0; k < GS_; ++k) {
    float a = an, b = bn;
    if (k + 1 < GS_) {
      an = a_sum[(c0 + k + 1) * 512 + d];
      bn = b_final[((size_t)(c0 + k + 1) * 16 + s) * 512 + d];
    }
    init[((size_t)(c0 + k) * 16 + s) * 512 + d] = h;
    h = fmaf(__expf(Ac * a), h, b);
  }
}

// p3 fuses ymod: writes final y = (scan_y + xm*D) * silu(z) into xz[:, :512]
__global__ __launch_bounds__(256) void scan_p3_kernel(const float* __restrict__ xdbl,
    const float* __restrict__ dt_w, const float* __restrict__ dt_b, const float* __restrict__ A_log,
    const float* __restrict__ init, const float* __restrict__ xm, const float* __restrict__ Dp,
    float* __restrict__ xz)
{
  const int d = blockIdx.x * 256 + threadIdx.x;
  const int c = blockIdx.y;
  float Ac[16];
#pragma unroll
  for (int s = 0; s < 16; ++s) Ac[s] = -__expf(A_log[d * 16 + s]);
  const float dwv = dt_w[d], dbv = dt_b[d], dpv = Dp[d];
  __shared__ float sx[CL_];
  __shared__ float sB[CL_][16];
  for (int idx = threadIdx.x; idx < CL_ * 17; idx += 256) {
    float v = xdbl[(size_t)c * (CL_ * 17) + idx];
    int row = idx / 17, col = idx - row * 17;
    if (col == 0) sx[row] = v; else sB[row][col - 1] = v;
  }
  __syncthreads();
  float h[16];
#pragma unroll
  for (int s = 0; s < 16; ++s) h[s] = init[((size_t)c * 16 + s) * 512 + d];
  for (int i = 0; i < CL_; ++i) {
    const int n = c * CL_ + i;
    float v = fmaf(sx[i], dwv, dbv);
    float dtv = fmaxf(v, 0.f) + log1pf(__expf(-fabsf(v)));
    float y = 0.f;
#pragma unroll
    for (int s = 0; s < 16; ++s) {
      float Bv = sB[i][s];
      h[s] = fmaf(__expf(Ac[s] * dtv), h[s], dtv * Bv);
      y = fmaf(h[s], Bv, y);
    }
    float yv = fmaf(xm[(size_t)n * 512 + d], dpv, y);
    float z = xz[(size_t)n * 1024 + 512 + d];
    xz[(size_t)n * 1024 + d] = yv * silu_f(z);
  }
}

// ================================================================ host
extern "C" void kernel_launch(void* const* d_in, const int* in_sizes, int n_in,
                              void* d_out, int out_size, void* d_ws, size_t ws_size,
                              hipStream_t stream)
{
  (void)in_sizes; (void)n_in; (void)out_size;
  const float* x         = (const float*)d_in[0];
  const int*   ei        = (const int*)d_in[1];
  const float* pnoise    = (const float*)d_in[2];
  const float* hop_w     = (const float*)d_in[3];
  const float* hop_b     = (const float*)d_in[4];
  const float* hop_ln_g  = (const float*)d_in[5];
  const float* hop_ln_b  = (const float*)d_in[6];
  const float* gat_w     = (const float*)d_in[7];
  const float* att_src   = (const float*)d_in[8];
  const float* att_dst   = (const float*)d_in[9];
  const float* gat_b     = (const float*)d_in[10];
  const float* in_proj_w = (const float*)d_in[11];
  const float* conv_w    = (const float*)d_in[12];
  const float* x_proj_w  = (const float*)d_in[13];
  const float* dt_w      = (const float*)d_in[14];
  const float* dt_b      = (const float*)d_in[15];
  const float* A_log     = (const float*)d_in[16];
  const float* D_param   = (const float*)d_in[17];
  const float* out_w     = (const float*)d_in[18];
  const float* out_b     = (const float*)d_in[19];
  const float* mlp_w1    = (const float*)d_in[20];
  const float* mlp_b1    = (const float*)d_in[21];
  const float* mlp_ln_g  = (const float*)d_in[22];
  const float* mlp_ln_b  = (const float*)d_in[23];
  const float* mlp_w2    = (const float*)d_in[24];
  const float* mlp_b2    = (const float*)d_in[25];
  float* out = (float*)d_out;

  char* w = (char*)d_ws;
  auto alloc = [&](size_t bytes) -> void* {
    void* p = (void*)w; w += (bytes + 255) & ~(size_t)255; return p;
  };
  float* xz   = (float*)alloc((size_t)N_ * 1024 * 4);  // 64 MiB
  float* xf   = (float*)alloc((size_t)N_ * 256 * 4);   // 16 MiB
  float* h    = (float*)alloc((size_t)N_ * 256 * 4);   // 16 MiB
  float* xm   = (float*)alloc((size_t)N_ * 512 * 4);   // 32 MiB
  float* cat  = (float*)alloc((size_t)N_ * 512 * 4);   // 32 MiB
  float* xdbl = (float*)alloc((size_t)N_ * 17 * 4);
  float* as_  = (float*)alloc((size_t)N_ * 4);
  float* ad_  = (float*)alloc((size_t)N_ * 4);
  int* cnt    = (int*)alloc((size_t)N_ * 4);    // cnt, degO, rank contiguous for one memset
  int* degO   = (int*)alloc((size_t)N_ * 4);
  int* rank   = (int*)alloc((size_t)N_ * 4);
  int* cursor = (int*)alloc((size_t)N_ * 4);
  int* off    = (int*)alloc((size_t)(N_ + 1) * 4);
  int* sidx   = (int*)alloc((size_t)N_ * 4);
  int* csr    = (int*)alloc((size_t)ET_ * 4);
  unsigned long long* keys = (unsigned long long*)alloc((size_t)N_ * 8);
  // scan group-operator buffers
  float* ga    = (float*)alloc((size_t)NG_ * 512 * 4);            // 64 KiB
  float* gb    = (float*)alloc((size_t)NG_ * 16 * 512 * 4);       // 1 MiB
  float* ginit = (float*)alloc((size_t)NG_ * 16 * 512 * 4);       // 1 MiB
  // bf16 transposed weight panels [Npad x K]
  unsigned short* bt_hop = (unsigned short*)alloc((size_t)256 * 768 * 2);
  unsigned short* bt_gat = (unsigned short*)alloc((size_t)256 * 256 * 2);
  unsigned short* bt_inp = (unsigned short*)alloc((size_t)1024 * 256 * 2);
  unsigned short* bt_xp  = (unsigned short*)alloc((size_t)64 * 512 * 2);
  unsigned short* bt_out = (unsigned short*)alloc((size_t)256 * 512 * 2);
  unsigned short* bt_m1  = (unsigned short*)alloc((size_t)256 * 512 * 2);
  unsigned short* bt_m2  = (unsigned short*)alloc((size_t)256 * 256 * 2);
  float* u0      = h;        // alias (h dead after gat_agg)
  float* mlp1    = xf;       // alias (xf dead after gather; mlp1 written step 15)
  float* b_final = h;        // alias (16 MiB; h dead after in_proj gemm)
  float* init    = xf;       // alias (16 MiB; xf dead after gather)
  float* a_sum   = (float*)csr;   // alias (1 MiB; csr dead after gat_agg)
  size_t needed = (size_t)(w - (char*)d_ws);
  if (needed > ws_size) {                    // diagnostic: absmax ~1e9 => ws too small
    marker_kernel<<<1, 256, 0, stream>>>(out);
    return;
  }

  hipMemsetAsync(cnt, 0, 3 * (size_t)N_ * 4, stream);   // cnt + degO + rank

  // 0. weight panels (bf16, transposed)
  wconv_kernel<<<dim3(24, 8),  256, 0, stream>>>(hop_w,     768, 256,  bt_hop);
  wconv_kernel<<<dim3(8, 8),   256, 0, stream>>>(gat_w,     256, 256,  bt_gat);
  wconv_kernel<<<dim3(8, 32),  256, 0, stream>>>(in_proj_w, 256, 1024, bt_inp);
  wconv_kernel<<<dim3(16, 2),  256, 0, stream>>>(x_proj_w,  512, 17,   bt_xp);
  wconv_kernel<<<dim3(16, 8),  256, 0, stream>>>(out_w,     512, 256,  bt_out);
  wconv_kernel<<<dim3(16, 8),  256, 0, stream>>>(mlp_w1,    512, 256,  bt_m1);
  wconv_kernel<<<dim3(8, 8),   256, 0, stream>>>(mlp_w2,    256, 256,  bt_m2);

  // 1. xcat = permute(x)
  permute_kernel<<<(3 * N_ * 64) / 256, 256, 0, stream>>>(x, xz);
  // 2. xf = silu(LN(xcat @ hop_w + hop_b))
  mgemm_kernel<<<dim3(128, 4), 256, 0, stream>>>(xz, 768, bt_hop, 768, 256, xf, 256, 0, hop_b, nullptr, 768);
  ln_silu_kernel<<<N_, 256, 0, stream>>>(xf, hop_ln_g, hop_ln_b);
  // 3. h = xf @ gat_w
  mgemm_kernel<<<dim3(128, 4), 256, 0, stream>>>(xf, 256, bt_gat, 256, 256, h, 256, 0, nullptr, nullptr, 256);
  // 4. attention logits per node
  att_scores_kernel<<<N_ / 4, 256, 0, stream>>>(h, att_src, att_dst, as_, ad_);
  // 5. CSR by dst (incl self loops) + out-degree
  count_kernel<<<(ET_ + 255) / 256, 256, 0, stream>>>(ei, cnt, degO);
  scan_offsets_kernel<<<1, 1024, 0, stream>>>(cnt, off, cursor);
  scatter_kernel<<<(ET_ + 255) / 256, 256, 0, stream>>>(ei, cursor, csr);
  // 6. GAT softmax+aggregate -> cat[:, :256]
  gat_agg_kernel<<<N_, 256, 0, stream>>>(ei, off, csr, as_, ad_, h, gat_b, cat);
  // 7. stable argsort(deg + noise*0.1)
  key_kernel<<<N_ / 256, 256, 0, stream>>>(degO, pnoise, keys);
  rank_part_kernel<<<dim3(N_ / 256, 32), 256, 0, stream>>>(keys, rank);
  rank_scatter_kernel<<<N_ / 256, 256, 0, stream>>>(rank, sidx);
  // 8. u0 = xf[sidx]; xz = u0 @ in_proj_w   (overwrites xcat)
  gather_kernel<<<N_, 64, 0, stream>>>(xf, sidx, u0);
  mgemm_kernel<<<dim3(128, 16), 256, 0, stream>>>(u0, 256, bt_inp, 256, 1024, xz, 1024, 0, nullptr, nullptr, 256);
  // 9. depthwise causal conv + silu -> xm
  conv_silu_kernel<<<(N_ * DI_) / 256, 256, 0, stream>>>(xz, conv_w, xm);
  // 10. x_dbl = xm @ x_proj_w (N=17)
  mgemm_kernel<<<dim3(128, 1), 256, 0, stream>>>(xm, 512, bt_xp, 512, 17, xdbl, 17, 0, nullptr, nullptr, 512);
  // 11+12+13. chunk-parallel selective scan, hierarchical mid -> xz[:, :512]
  scan_p1_kernel<<<dim3(2, CH_), 256, 0, stream>>>(xdbl, dt_w, dt_b, A_log, a_sum, b_final);
  scan_mid1_kernel<<<(NG_ * 16 * 512) / 256, 256, 0, stream>>>(a_sum, b_final, A_log, ga, gb);
  scan_mid2_kernel<<<32, 256, 0, stream>>>(ga, gb, A_log, ginit);
  scan_mid3_kernel<<<(NG_ * 16 * 512) / 256, 256, 0, stream>>>(a_sum, b_final, A_log, ginit, init);
  scan_p3_kernel<<<dim3(2, CH_), 256, 0, stream>>>(xdbl, dt_w, dt_b, A_log, init, xm, D_param, xz);
  // 14. x_mamba = y @ out_w + out_b, scattered (un-permuted) into cat[:, 256:]
  mgemm_kernel<<<dim3(128, 4), 256, 0, stream>>>(xz, 1024, bt_out, 512, 256, cat, 512, 256, out_b, sidx, 512);
  // 15. MLP
  mgemm_kernel<<<dim3(128, 4), 256, 0, stream>>>(cat, 512, bt_m1, 512, 256, mlp1, 256, 0, mlp_b1, nullptr, 512);
  ln_silu_kernel<<<N_, 256, 0, stream>>>(mlp1, mlp_ln_g, mlp_ln_b);
  mgemm_kernel<<<dim3(128, 4), 256, 0, stream>>>(mlp1, 256, bt_m2, 256, 256, out, 256, 0, mlp_b2, nullptr, 256);
}

// Round 8
// 501.180 us; speedup vs baseline: 1.1584x; 1.0237x over previous
//
#include <hip/hip_runtime.h>

#define N_   16384
#define D_   256
#define E_   262144
#define ET_  278528   // E_ + N_ (self loops)
#define DI_  512
#define CH_  512      // scan chunks
#define CL_  32       // chunk length (CH_*CL_ == N_)
#define GS_  16       // chunk-operator group size
#define NG_  32       // number of groups (CH_/GS_)

typedef __attribute__((ext_vector_type(8))) short short8;
typedef __attribute__((ext_vector_type(4))) float f32x4;

static __device__ __forceinline__ float wave_sum(float v){
#pragma unroll
  for (int m = 1; m < 64; m <<= 1) v += __shfl_xor(v, m);
  return v;
}
static __device__ __forceinline__ float wave_max(float v){
#pragma unroll
  for (int m = 1; m < 64; m <<= 1) v = fmaxf(v, __shfl_xor(v, m));
  return v;
}
static __device__ __forceinline__ float silu_f(float x){ return x / (1.f + __expf(-x)); }
static __device__ __forceinline__ float softplus_f(float v){   // cheap: 2 HW transcendentals
  return fmaxf(v, 0.f) + __logf(1.f + __expf(-fabsf(v)));
}
static __device__ __forceinline__ unsigned short f2b(float f){   // fp32 -> bf16 RNE
  unsigned u = __float_as_uint(f);
  return (unsigned short)((u + 0x7fffu + ((u >> 16) & 1u)) >> 16);
}

// ---------------------------------------------------------------- diagnostic marker (fires only if ws too small)
__global__ __launch_bounds__(256) void marker_kernel(float* __restrict__ out){
  out[threadIdx.x] = 1e9f;
}

// ---------------------------------------------------------------- permute x (3,N,256) -> xcat (N,768)
__global__ __launch_bounds__(256) void permute_kernel(const float* __restrict__ x, float* __restrict__ xcat){
  int idx = blockIdx.x * 256 + threadIdx.x;      // over 3*16384*64 float4
  if (idx >= 3 * N_ * 64) return;
  int d4  = idx & 63;
  int n   = (idx >> 6) & (N_ - 1);
  int hop = idx >> 20;
  float4 v = ((const float4*)x)[((size_t)hop << 20) + ((size_t)n << 6) + d4];
  ((float4*)xcat)[(size_t)n * 192 + hop * 64 + d4] = v;
}

// ---------------------------------------------------------------- weight transpose+convert: W[K x N] fp32 -> BT[Npad x K] bf16
__global__ __launch_bounds__(256) void wconv_kernel(const float* __restrict__ W, int K, int N,
                                                    unsigned short* __restrict__ BT){
  __shared__ float t[32][33];
  const int k0 = blockIdx.x * 32, n0 = blockIdx.y * 32;
  const int tr = threadIdx.x & 31, tc = threadIdx.x >> 5;
#pragma unroll
  for (int r = tc; r < 32; r += 8) {
    int k = k0 + r, n = n0 + tr;
    t[r][tr] = (k < K && n < N) ? W[(size_t)k * N + n] : 0.f;
  }
  __syncthreads();
#pragma unroll
  for (int r = tc; r < 32; r += 8) {
    int n = n0 + r, k = k0 + tr;
    BT[(size_t)n * K + k] = f2b(t[tr][r]);
  }
}

// ---------------------------------------------------------------- bf16 MFMA GEMM
// C[row_map[m], c_off+n] = A(M x K fp32) @ BT^T (BT is [Npad x K] bf16) + bias
// tile 128x64, 4 waves (2x2), per-wave 64x32 = 4x2 frags of 16x16, BK=32.
#define ALD 40   // LDS row stride in bf16 elems (80B): 16B aligned, <=2-way bank conflict
__global__ __launch_bounds__(256) void mgemm_kernel(
    const float* __restrict__ A, int lda,
    const unsigned short* __restrict__ BT, int ldbt, int N,
    float* __restrict__ C, int ldc, int c_off,
    const float* __restrict__ bias, const int* __restrict__ row_map, int K)
{
  __shared__ __align__(16) unsigned short Al[128 * ALD];
  __shared__ __align__(16) unsigned short Bl[64 * ALD];
  const int tid = threadIdx.x;
  const int lane = tid & 63;
  const int wid = tid >> 6;
  const int wr = wid >> 1;           // wave row half (64 rows)
  const int wc = wid & 1;            // wave col half (32 cols)
  const int m0 = blockIdx.x * 128;
  const int n0 = blockIdx.y * 64;
  const int fr = lane & 15, fq = lane >> 4;
  f32x4 acc[4][2] = {};
  for (int k0 = 0; k0 < K; k0 += 32) {
    // stage A: 128x32 fp32 -> bf16 (4 float4 per thread)
#pragma unroll
    for (int i = 0; i < 4; ++i) {
      int f = tid + i * 256;                 // 0..1023
      int r = f >> 3, kq = (f & 7) << 2;
      float4 v = *(const float4*)&A[(size_t)(m0 + r) * lda + k0 + kq];
      unsigned long long pk = (unsigned long long)f2b(v.x)
                            | ((unsigned long long)f2b(v.y) << 16)
                            | ((unsigned long long)f2b(v.z) << 32)
                            | ((unsigned long long)f2b(v.w) << 48);
      *(unsigned long long*)&Al[r * ALD + kq] = pk;
    }
    // stage BT: 64 cols x 32 k bf16 (16B per thread)
    {
      int c = tid >> 2, kq = (tid & 3) << 3;
      short8 v = *(const short8*)&BT[(size_t)(n0 + c) * ldbt + k0 + kq];
      *(short8*)&Bl[c * ALD + kq] = v;
    }
    __syncthreads();
    short8 af[4], bf[2];
#pragma unroll
    for (int m = 0; m < 4; ++m) af[m] = *(const short8*)&Al[(wr * 64 + m * 16 + fr) * ALD + fq * 8];
#pragma unroll
    for (int n = 0; n < 2; ++n) bf[n] = *(const short8*)&Bl[(wc * 32 + n * 16 + fr) * ALD + fq * 8];
#pragma unroll
    for (int n = 0; n < 2; ++n)
#pragma unroll
      for (int m = 0; m < 4; ++m)
        acc[m][n] = __builtin_amdgcn_mfma_f32_16x16x32_bf16(af[m], bf[n], acc[m][n], 0, 0, 0);
    __syncthreads();
  }
  // epilogue: C col=lane&15, row=(lane>>4)*4+j  [m89-verified]
#pragma unroll
  for (int m = 0; m < 4; ++m)
#pragma unroll
    for (int n = 0; n < 2; ++n) {
      int col = n0 + wc * 32 + n * 16 + fr;
      if (col >= N) continue;
      float bv = bias ? bias[col] : 0.f;
#pragma unroll
      for (int j = 0; j < 4; ++j) {
        int row = m0 + wr * 64 + m * 16 + fq * 4 + j;
        int orow = row_map ? row_map[row] : row;
        C[(size_t)orow * ldc + c_off + col] = acc[m][n][j] + bv;
      }
    }
}

// ---------------------------------------------------------------- rowwise LN(256) + silu, in place
__global__ __launch_bounds__(256) void ln_silu_kernel(float* __restrict__ x, const float* __restrict__ g, const float* __restrict__ b){
  __shared__ float red[4];
  const int row = blockIdx.x; const int t = threadIdx.x;
  float v = x[(size_t)row * 256 + t];
  float sv = wave_sum(v);
  if ((t & 63) == 0) red[t >> 6] = sv;
  __syncthreads();
  float mean = (red[0] + red[1] + red[2] + red[3]) * (1.f / 256.f);
  __syncthreads();
  float dv = v - mean;
  float sq = wave_sum(dv * dv);
  if ((t & 63) == 0) red[t >> 6] = sq;
  __syncthreads();
  float var = (red[0] + red[1] + red[2] + red[3]) * (1.f / 256.f);
  float o = dv * rsqrtf(var + 1e-5f) * g[t] + b[t];
  x[(size_t)row * 256 + t] = silu_f(o);
}

// ---------------------------------------------------------------- per-node attention logits
__global__ __launch_bounds__(256) void att_scores_kernel(const float* __restrict__ h, const float* __restrict__ asr,
                                                         const float* __restrict__ adt, float* __restrict__ as_, float* __restrict__ ad_){
  int wid = threadIdx.x >> 6, lane = threadIdx.x & 63;
  int n = blockIdx.x * 4 + wid;
  float s1 = 0.f, s2 = 0.f;
  for (int f = lane; f < 256; f += 64) {
    float hv = h[(size_t)n * 256 + f];
    s1 = fmaf(hv, asr[f], s1); s2 = fmaf(hv, adt[f], s2);
  }
  s1 = wave_sum(s1); s2 = wave_sum(s2);
  if (lane == 0) { as_[n] = s1; ad_[n] = s2; }
}

// ---------------------------------------------------------------- CSR build
__global__ __launch_bounds__(256) void count_kernel(const int* __restrict__ ei, int* __restrict__ cnt_in, int* __restrict__ deg_out){
  int i = blockIdx.x * 256 + threadIdx.x;
  if (i >= ET_) return;
  int dst = (i < E_) ? ei[E_ + i] : (i - E_);
  atomicAdd(&cnt_in[dst], 1);
  if (i < E_) atomicAdd(&deg_out[ei[i]], 1);
}

__global__ __launch_bounds__(1024) void scan_offsets_kernel(const int* __restrict__ cnt, int* __restrict__ off, int* __restrict__ cursor){
  __shared__ int part[1024];
  int t = threadIdx.x;
  int base = t * 16;
  int local[16]; int s = 0;
#pragma unroll
  for (int i = 0; i < 16; ++i) { local[i] = s; s += cnt[base + i]; }
  part[t] = s; __syncthreads();
  for (int d = 1; d < 1024; d <<= 1) {
    int val = part[t];
    int add = (t >= d) ? part[t - d] : 0;
    __syncthreads();
    part[t] = val + add;
    __syncthreads();
  }
  int prev = (t > 0) ? part[t - 1] : 0;
#pragma unroll
  for (int i = 0; i < 16; ++i) { int o = prev + local[i]; off[base + i] = o; cursor[base + i] = o; }
  if (t == 1023) off[N_] = part[1023];
}

__global__ __launch_bounds__(256) void scatter_kernel(const int* __restrict__ ei, int* __restrict__ cursor, int* __restrict__ csr){
  int i = blockIdx.x * 256 + threadIdx.x;
  if (i >= ET_) return;
  int dst = (i < E_) ? ei[E_ + i] : (i - E_);
  int pos = atomicAdd(&cursor[dst], 1);
  csr[pos] = i;
}

// ---------------------------------------------------------------- GAT softmax + aggregate (gather, no float atomics). writes cat[:, :256]
__global__ __launch_bounds__(256) void gat_agg_kernel(const int* __restrict__ ei, const int* __restrict__ off, const int* __restrict__ csr,
                                                      const float* __restrict__ as_, const float* __restrict__ ad_,
                                                      const float* __restrict__ h, const float* __restrict__ gat_b, float* __restrict__ cat){
  const int dst = blockIdx.x;
  const int t = threadIdx.x;
  const int o0 = off[dst];
  int deg = off[dst + 1] - o0;
  if (deg > 1024) deg = 1024;   // cannot occur (mean deg ~17); guards LDS
  __shared__ int   ssrc[1024];
  __shared__ float se[1024];
  __shared__ float red[4];
  const float adv = ad_[dst];
  float m = -1e30f;
  for (int j = t; j < deg; j += 256) {
    int eid = csr[o0 + j];
    int src = (eid < E_) ? ei[eid] : (eid - E_);
    float e = as_[src] + adv;
    e = (e >= 0.f) ? e : 0.2f * e;
    ssrc[j] = src; se[j] = e;
    m = fmaxf(m, e);
  }
  m = wave_max(m);
  if ((t & 63) == 0) red[t >> 6] = m;
  __syncthreads();
  m = fmaxf(fmaxf(red[0], red[1]), fmaxf(red[2], red[3]));
  __syncthreads();
  float dsum = 0.f;
  for (int j = t; j < deg; j += 256) { float x = __expf(se[j] - m); se[j] = x; dsum += x; }
  dsum = wave_sum(dsum);
  if ((t & 63) == 0) red[t >> 6] = dsum;
  __syncthreads();
  float inv = 1.f / (red[0] + red[1] + red[2] + red[3]);
  float acc = gat_b[t];
  for (int j = 0; j < deg; ++j) acc = fmaf(se[j] * inv, h[(size_t)ssrc[j] * 256 + t], acc);
  cat[(size_t)dst * 512 + t] = acc;
}

// ---------------------------------------------------------------- sort key: (enc32(deg + noise*0.1) << 32) | idx
__global__ __launch_bounds__(256) void key_kernel(const int* __restrict__ degO, const float* __restrict__ noise, unsigned long long* __restrict__ keys){
  int n = blockIdx.x * 256 + threadIdx.x;
  if (n >= N_) return;
  float k = __fadd_rn((float)degO[n], __fmul_rn(noise[n], 0.1f));
  unsigned u = __float_as_uint(k);
  u = (u & 0x80000000u) ? ~u : (u | 0x80000000u);
  keys[n] = ((unsigned long long)u << 32) | (unsigned)n;
}

// ---------------------------------------------------------------- O(N^2) rank sort, j-split for occupancy
__global__ __launch_bounds__(256) void rank_part_kernel(const unsigned long long* __restrict__ keys, int* __restrict__ rank){
  __shared__ unsigned long long tile[512];
  const int i = blockIdx.x * 256 + threadIdx.x;
  const unsigned long long ki = keys[i];
  const int base = blockIdx.y * 512;
  for (int j = threadIdx.x; j < 512; j += 256) tile[j] = keys[base + j];
  __syncthreads();
  int r = 0;
#pragma unroll 16
  for (int j = 0; j < 512; ++j) r += (tile[j] < ki);
  atomicAdd(&rank[i], r);
}
__global__ __launch_bounds__(256) void rank_scatter_kernel(const int* __restrict__ rank, int* __restrict__ sidx){
  int i = blockIdx.x * 256 + threadIdx.x;
  sidx[rank[i]] = i;
}

// ---------------------------------------------------------------- u0 = xf[sidx]
__global__ __launch_bounds__(64) void gather_kernel(const float* __restrict__ xf, const int* __restrict__ sidx, float* __restrict__ u0){
  int i = blockIdx.x, t = threadIdx.x;
  ((float4*)u0)[(size_t)i * 64 + t] = ((const float4*)xf)[(size_t)sidx[i] * 64 + t];
}

// ---------------------------------------------------------------- causal depthwise conv (k=4) + silu; in = xz[:, :512] (stride 1024)
__global__ __launch_bounds__(256) void conv_silu_kernel(const float* __restrict__ xz, const float* __restrict__ cw, float* __restrict__ xm){
  int idx = blockIdx.x * 256 + threadIdx.x;
  if (idx >= N_ * DI_) return;
  int n = idx >> 9, c = idx & 511;
  float acc = 0.f;
#pragma unroll
  for (int k = 0; k < 4; ++k) {
    int nn = n - 3 + k;
    if (nn >= 0) acc = fmaf(xz[(size_t)nn * 1024 + c], cw[c * 4 + k], acc);
  }
  xm[idx] = silu_f(acc);
}

// ================================================================ chunk-parallel selective scan
// h[s] = exp(Ac[s]*dt)*h[s] + dt*B[s]; y[n,d] = sum_s h[s]*B[n,s].
// p1/p3: 512 threads, thread = (d, s-half): 8 states/thread, y via shfl_xor(1).
// layouts: b_final/init [c][s][d]; group ops ga[g][d], gb[g][s][d]; d fastest.
__global__ __launch_bounds__(512) void scan_p1_kernel(const float* __restrict__ xdbl,
    const float* __restrict__ dt_w, const float* __restrict__ dt_b, const float* __restrict__ A_log,
    float* __restrict__ a_sum, float* __restrict__ b_final)
{
  const int t = threadIdx.x;
  const int d = blockIdx.x * 256 + (t >> 1);
  const int sh = (t & 1) * 8;          // owned state range [sh, sh+8)
  const int c = blockIdx.y;
  float Ac2[8];
#pragma unroll
  for (int k = 0; k < 8; ++k) Ac2[k] = -__expf(A_log[d * 16 + sh + k]) * 1.44269504f;
  const float dwv = dt_w[d], dbv = dt_b[d];
  __shared__ float sx[CL_];
  __shared__ __align__(16) float sB[CL_][16];
  for (int idx = t; idx < CL_ * 17; idx += 512) {
    float v = xdbl[(size_t)c * (CL_ * 17) + idx];
    int row = idx / 17, col = idx - row * 17;
    if (col == 0) sx[row] = v; else sB[row][col - 1] = v;
  }
  __syncthreads();
  float h[8] = {};
  float dts = 0.f;
  for (int i = 0; i < CL_; ++i) {
    float dtv = softplus_f(fmaf(sx[i], dwv, dbv));
    dts += dtv;
    float4 b0 = *(const float4*)&sB[i][sh];
    float4 b1 = *(const float4*)&sB[i][sh + 4];
    h[0] = fmaf(exp2f(Ac2[0] * dtv), h[0], dtv * b0.x);
    h[1] = fmaf(exp2f(Ac2[1] * dtv), h[1], dtv * b0.y);
    h[2] = fmaf(exp2f(Ac2[2] * dtv), h[2], dtv * b0.z);
    h[3] = fmaf(exp2f(Ac2[3] * dtv), h[3], dtv * b0.w);
    h[4] = fmaf(exp2f(Ac2[4] * dtv), h[4], dtv * b1.x);
    h[5] = fmaf(exp2f(Ac2[5] * dtv), h[5], dtv * b1.y);
    h[6] = fmaf(exp2f(Ac2[6] * dtv), h[6], dtv * b1.z);
    h[7] = fmaf(exp2f(Ac2[7] * dtv), h[7], dtv * b1.w);
  }
  if ((t & 1) == 0) a_sum[c * 512 + d] = dts;
#pragma unroll
  for (int k = 0; k < 8; ++k) b_final[((size_t)c * 16 + sh + k) * 512 + d] = h[k];
}

// mid level 1: compose GS_ chunk ops per group -> (ga, gb)
__global__ __launch_bounds__(256) void scan_mid1_kernel(const float* __restrict__ a_sum,
    const float* __restrict__ b_final, const float* __restrict__ A_log,
    float* __restrict__ ga, float* __restrict__ gb)
{
  const int tid = blockIdx.x * 256 + threadIdx.x;   // NG_*16*512
  const int d = tid & 511;
  const int s = (tid >> 9) & 15;
  const int g = tid >> 13;
  const float Ac = -__expf(A_log[d * 16 + s]);
  const int c0 = g * GS_;
  float ag = 0.f, Bg = 0.f;
  float an = a_sum[c0 * 512 + d];
  float bn = b_final[((size_t)c0 * 16 + s) * 512 + d];
#pragma unroll
  for (int k = 0; k < GS_; ++k) {
    float a = an, b = bn;
    if (k + 1 < GS_) {
      an = a_sum[(c0 + k + 1) * 512 + d];
      bn = b_final[((size_t)(c0 + k + 1) * 16 + s) * 512 + d];
    }
    Bg = fmaf(__expf(Ac * a), Bg, b);
    ag += a;
  }
  gb[((size_t)g * 16 + s) * 512 + d] = Bg;
  if (s == 0) ga[g * 512 + d] = ag;
}

// mid level 2: scan NG_ group ops fully in registers (static unroll)
__global__ __launch_bounds__(256) void scan_mid2_kernel(const float* __restrict__ ga,
    const float* __restrict__ gb, const float* __restrict__ A_log, float* __restrict__ ginit)
{
  const int tid = blockIdx.x * 256 + threadIdx.x;   // 8192 = (s,d)
  const int d = tid & 511;
  const int s = tid >> 9;
  const float Ac = -__expf(A_log[d * 16 + s]);
  float gar[NG_], gbr[NG_];
#pragma unroll
  for (int g = 0; g < NG_; ++g) {
    gar[g] = ga[g * 512 + d];
    gbr[g] = gb[((size_t)g * 16 + s) * 512 + d];
  }
  float h = 0.f;
#pragma unroll
  for (int g = 0; g < NG_; ++g) {
    ginit[((size_t)g * 16 + s) * 512 + d] = h;
    h = fmaf(__expf(Ac * gar[g]), h, gbr[g]);
  }
}

// mid level 3: expand group-entry states to per-chunk init
__global__ __launch_bounds__(256) void scan_mid3_kernel(const float* __restrict__ a_sum,
    const float* __restrict__ b_final, const float* __restrict__ A_log,
    const float* __restrict__ ginit, float* __restrict__ init)
{
  const int tid = blockIdx.x * 256 + threadIdx.x;
  const int d = tid & 511;
  const int s = (tid >> 9) & 15;
  const int g = tid >> 13;
  const float Ac = -__expf(A_log[d * 16 + s]);
  const int c0 = g * GS_;
  float h = ginit[((size_t)g * 16 + s) * 512 + d];
  float an = a_sum[c0 * 512 + d];
  float bn = b_final[((size_t)c0 * 16 + s) * 512 + d];
#pragma unroll
  for (int k = 0; k < GS_; ++k) {
    float a = an, b = bn;
    if (k + 1 < GS_) {
      an = a_sum[(c0 + k + 1) * 512 + d];
      bn = b_final[((size_t)(c0 + k + 1) * 16 + s) * 512 + d];
    }
    init[((size_t)(c0 + k) * 16 + s) * 512 + d] = h;
    h = fmaf(__expf(Ac * a), h, b);
  }
}

// p3 fuses ymod: writes final y = (scan_y + xm*D) * silu(z) into xz[:, :512]
__global__ __launch_bounds__(512) void scan_p3_kernel(const float* __restrict__ xdbl,
    const float* __restrict__ dt_w, const float* __restrict__ dt_b, const float* __restrict__ A_log,
    const float* __restrict__ init, const float* __restrict__ xm, const float* __restrict__ Dp,
    float* __restrict__ xz)
{
  const int t = threadIdx.x;
  const int d = blockIdx.x * 256 + (t >> 1);
  const int sh = (t & 1) * 8;
  const int c = blockIdx.y;
  float Ac2[8];
#pragma unroll
  for (int k = 0; k < 8; ++k) Ac2[k] = -__expf(A_log[d * 16 + sh + k]) * 1.44269504f;
  const float dwv = dt_w[d], dbv = dt_b[d], dpv = Dp[d];
  __shared__ float sx[CL_];
  __shared__ __align__(16) float sB[CL_][16];
  for (int idx = t; idx < CL_ * 17; idx += 512) {
    float v = xdbl[(size_t)c * (CL_ * 17) + idx];
    int row = idx / 17, col = idx - row * 17;
    if (col == 0) sx[row] = v; else sB[row][col - 1] = v;
  }
  __syncthreads();
  float h[8];
#pragma unroll
  for (int k = 0; k < 8; ++k) h[k] = init[((size_t)c * 16 + sh + k) * 512 + d];
  for (int i = 0; i < CL_; ++i) {
    const int n = c * CL_ + i;
    float dtv = softplus_f(fmaf(sx[i], dwv, dbv));
    float4 b0 = *(const float4*)&sB[i][sh];
    float4 b1 = *(const float4*)&sB[i][sh + 4];
    h[0] = fmaf(exp2f(Ac2[0] * dtv), h[0], dtv * b0.x);
    h[1] = fmaf(exp2f(Ac2[1] * dtv), h[1], dtv * b0.y);
    h[2] = fmaf(exp2f(Ac2[2] * dtv), h[2], dtv * b0.z);
    h[3] = fmaf(exp2f(Ac2[3] * dtv), h[3], dtv * b0.w);
    h[4] = fmaf(exp2f(Ac2[4] * dtv), h[4], dtv * b1.x);
    h[5] = fmaf(exp2f(Ac2[5] * dtv), h[5], dtv * b1.y);
    h[6] = fmaf(exp2f(Ac2[6] * dtv), h[6], dtv * b1.z);
    h[7] = fmaf(exp2f(Ac2[7] * dtv), h[7], dtv * b1.w);
    float y = h[0] * b0.x;
    y = fmaf(h[1], b0.y, y); y = fmaf(h[2], b0.z, y); y = fmaf(h[3], b0.w, y);
    y = fmaf(h[4], b1.x, y); y = fmaf(h[5], b1.y, y); y = fmaf(h[6], b1.z, y);
    y = fmaf(h[7], b1.w, y);
    y += __shfl_xor(y, 1);             // combine the two s-halves
    if ((t & 1) == 0) {
      float yv = fmaf(xm[(size_t)n * 512 + d], dpv, y);
      float z = xz[(size_t)n * 1024 + 512 + d];
      xz[(size_t)n * 1024 + d] = yv * silu_f(z);
    }
  }
}

// ================================================================ host
extern "C" void kernel_launch(void* const* d_in, const int* in_sizes, int n_in,
                              void* d_out, int out_size, void* d_ws, size_t ws_size,
                              hipStream_t stream)
{
  (void)in_sizes; (void)n_in; (void)out_size;
  const float* x         = (const float*)d_in[0];
  const int*   ei        = (const int*)d_in[1];
  const float* pnoise    = (const float*)d_in[2];
  const float* hop_w     = (const float*)d_in[3];
  const float* hop_b     = (const float*)d_in[4];
  const float* hop_ln_g  = (const float*)d_in[5];
  const float* hop_ln_b  = (const float*)d_in[6];
  const float* gat_w     = (const float*)d_in[7];
  const float* att_src   = (const float*)d_in[8];
  const float* att_dst   = (const float*)d_in[9];
  const float* gat_b     = (const float*)d_in[10];
  const float* in_proj_w = (const float*)d_in[11];
  const float* conv_w    = (const float*)d_in[12];
  const float* x_proj_w  = (const float*)d_in[13];
  const float* dt_w      = (const float*)d_in[14];
  const float* dt_b      = (const float*)d_in[15];
  const float* A_log     = (const float*)d_in[16];
  const float* D_param   = (const float*)d_in[17];
  const float* out_w     = (const float*)d_in[18];
  const float* out_b     = (const float*)d_in[19];
  const float* mlp_w1    = (const float*)d_in[20];
  const float* mlp_b1    = (const float*)d_in[21];
  const float* mlp_ln_g  = (const float*)d_in[22];
  const float* mlp_ln_b  = (const float*)d_in[23];
  const float* mlp_w2    = (const float*)d_in[24];
  const float* mlp_b2    = (const float*)d_in[25];
  float* out = (float*)d_out;

  char* w = (char*)d_ws;
  auto alloc = [&](size_t bytes) -> void* {
    void* p = (void*)w; w += (bytes + 255) & ~(size_t)255; return p;
  };
  float* xz   = (float*)alloc((size_t)N_ * 1024 * 4);  // 64 MiB
  float* xf   = (float*)alloc((size_t)N_ * 256 * 4);   // 16 MiB
  float* h    = (float*)alloc((size_t)N_ * 256 * 4);   // 16 MiB
  float* xm   = (float*)alloc((size_t)N_ * 512 * 4);   // 32 MiB
  float* cat  = (float*)alloc((size_t)N_ * 512 * 4);   // 32 MiB
  float* xdbl = (float*)alloc((size_t)N_ * 17 * 4);
  float* as_  = (float*)alloc((size_t)N_ * 4);
  float* ad_  = (float*)alloc((size_t)N_ * 4);
  int* cnt    = (int*)alloc((size_t)N_ * 4);    // cnt, degO, rank contiguous for one memset
  int* degO   = (int*)alloc((size_t)N_ * 4);
  int* rank   = (int*)alloc((size_t)N_ * 4);
  int* cursor = (int*)alloc((size_t)N_ * 4);
  int* off    = (int*)alloc((size_t)(N_ + 1) * 4);
  int* sidx   = (int*)alloc((size_t)N_ * 4);
  int* csr    = (int*)alloc((size_t)ET_ * 4);
  unsigned long long* keys = (unsigned long long*)alloc((size_t)N_ * 8);
  // scan group-operator buffers
  float* ga    = (float*)alloc((size_t)NG_ * 512 * 4);            // 64 KiB
  float* gb    = (float*)alloc((size_t)NG_ * 16 * 512 * 4);       // 1 MiB
  float* ginit = (float*)alloc((size_t)NG_ * 16 * 512 * 4);       // 1 MiB
  // bf16 transposed weight panels [Npad x K]
  unsigned short* bt_hop = (unsigned short*)alloc((size_t)256 * 768 * 2);
  unsigned short* bt_gat = (unsigned short*)alloc((size_t)256 * 256 * 2);
  unsigned short* bt_inp = (unsigned short*)alloc((size_t)1024 * 256 * 2);
  unsigned short* bt_xp  = (unsigned short*)alloc((size_t)64 * 512 * 2);
  unsigned short* bt_out = (unsigned short*)alloc((size_t)256 * 512 * 2);
  unsigned short* bt_m1  = (unsigned short*)alloc((size_t)256 * 512 * 2);
  unsigned short* bt_m2  = (unsigned short*)alloc((size_t)256 * 256 * 2);
  float* u0      = h;        // alias (h dead after gat_agg)
  float* mlp1    = xf;       // alias (xf dead after gather; mlp1 written step 15)
  float* b_final = h;        // alias (16 MiB; h dead after in_proj gemm)
  float* init    = xf;       // alias (16 MiB; xf dead after gather)
  float* a_sum   = (float*)csr;   // alias (1 MiB; csr dead after gat_agg)
  size_t needed = (size_t)(w - (char*)d_ws);
  if (needed > ws_size) {                    // diagnostic: absmax ~1e9 => ws too small
    marker_kernel<<<1, 256, 0, stream>>>(out);
    return;
  }

  hipMemsetAsync(cnt, 0, 3 * (size_t)N_ * 4, stream);   // cnt + degO + rank

  // 0. weight panels (bf16, transposed)
  wconv_kernel<<<dim3(24, 8),  256, 0, stream>>>(hop_w,     768, 256,  bt_hop);
  wconv_kernel<<<dim3(8, 8),   256, 0, stream>>>(gat_w,     256, 256,  bt_gat);
  wconv_kernel<<<dim3(8, 32),  256, 0, stream>>>(in_proj_w, 256, 1024, bt_inp);
  wconv_kernel<<<dim3(16, 2),  256, 0, stream>>>(x_proj_w,  512, 17,   bt_xp);
  wconv_kernel<<<dim3(16, 8),  256, 0, stream>>>(out_w,     512, 256,  bt_out);
  wconv_kernel<<<dim3(16, 8),  256, 0, stream>>>(mlp_w1,    512, 256,  bt_m1);
  wconv_kernel<<<dim3(8, 8),   256, 0, stream>>>(mlp_w2,    256, 256,  bt_m2);

  // 1. xcat = permute(x)
  permute_kernel<<<(3 * N_ * 64) / 256, 256, 0, stream>>>(x, xz);
  // 2. xf = silu(LN(xcat @ hop_w + hop_b))
  mgemm_kernel<<<dim3(128, 4), 256, 0, stream>>>(xz, 768, bt_hop, 768, 256, xf, 256, 0, hop_b, nullptr, 768);
  ln_silu_kernel<<<N_, 256, 0, stream>>>(xf, hop_ln_g, hop_ln_b);
  // 3. h = xf @ gat_w
  mgemm_kernel<<<dim3(128, 4), 256, 0, stream>>>(xf, 256, bt_gat, 256, 256, h, 256, 0, nullptr, nullptr, 256);
  // 4. attention logits per node
  att_scores_kernel<<<N_ / 4, 256, 0, stream>>>(h, att_src, att_dst, as_, ad_);
  // 5. CSR by dst (incl self loops) + out-degree
  count_kernel<<<(ET_ + 255) / 256, 256, 0, stream>>>(ei, cnt, degO);
  scan_offsets_kernel<<<1, 1024, 0, stream>>>(cnt, off, cursor);
  scatter_kernel<<<(ET_ + 255) / 256, 256, 0, stream>>>(ei, cursor, csr);
  // 6. GAT softmax+aggregate -> cat[:, :256]
  gat_agg_kernel<<<N_, 256, 0, stream>>>(ei, off, csr, as_, ad_, h, gat_b, cat);
  // 7. stable argsort(deg + noise*0.1)
  key_kernel<<<N_ / 256, 256, 0, stream>>>(degO, pnoise, keys);
  rank_part_kernel<<<dim3(N_ / 256, 32), 256, 0, stream>>>(keys, rank);
  rank_scatter_kernel<<<N_ / 256, 256, 0, stream>>>(rank, sidx);
  // 8. u0 = xf[sidx]; xz = u0 @ in_proj_w   (overwrites xcat)
  gather_kernel<<<N_, 64, 0, stream>>>(xf, sidx, u0);
  mgemm_kernel<<<dim3(128, 16), 256, 0, stream>>>(u0, 256, bt_inp, 256, 1024, xz, 1024, 0, nullptr, nullptr, 256);
  // 9. depthwise causal conv + silu -> xm
  conv_silu_kernel<<<(N_ * DI_) / 256, 256, 0, stream>>>(xz, conv_w, xm);
  // 10. x_dbl = xm @ x_proj_w (N=17)
  mgemm_kernel<<<dim3(128, 1), 256, 0, stream>>>(xm, 512, bt_xp, 512, 17, xdbl, 17, 0, nullptr, nullptr, 512);
  // 11+12+13. chunk-parallel selective scan, hierarchical mid -> xz[:, :512]
  scan_p1_kernel<<<dim3(2, CH_), 512, 0, stream>>>(xdbl, dt_w, dt_b, A_log, a_sum, b_final);
  scan_mid1_kernel<<<(NG_ * 16 * 512) / 256, 256, 0, stream>>>(a_sum, b_final, A_log, ga, gb);
  scan_mid2_kernel<<<32, 256, 0, stream>>>(ga, gb, A_log, ginit);
  scan_mid3_kernel<<<(NG_ * 16 * 512) / 256, 256, 0, stream>>>(a_sum, b_final, A_log, ginit, init);
  scan_p3_kernel<<<dim3(2, CH_), 512, 0, stream>>>(xdbl, dt_w, dt_b, A_log, init, xm, D_param, xz);
  // 14. x_mamba = y @ out_w + out_b, scattered (un-permuted) into cat[:, 256:]
  mgemm_kernel<<<dim3(128, 4), 256, 0, stream>>>(xz, 1024, bt_out, 512, 256, cat, 512, 256, out_b, sidx, 512);
  // 15. MLP
  mgemm_kernel<<<dim3(128, 4), 256, 0, stream>>>(cat, 512, bt_m1, 512, 256, mlp1, 256, 0, mlp_b1, nullptr, 512);
  ln_silu_kernel<<<N_, 256, 0, stream>>>(mlp1, mlp_ln_g, mlp_ln_b);
  mgemm_kernel<<<dim3(128, 4), 256, 0, stream>>>(mlp1, 256, bt_m2, 256, 256, out, 256, 0, mlp_b2, nullptr, 256);
}